// Round 4
// baseline (482.814 us; speedup 1.0000x reference)
//
#include <hip/hip_runtime.h>
#include <hip/hip_bf16.h>

#define O_DIM 8192
#define I_DIM 8192
#define G_DIM 64
#define RANK  128

typedef __bf16 bf16x8 __attribute__((ext_vector_type(8)));
typedef __bf16 bf16x4 __attribute__((ext_vector_type(4)));
typedef float  f32x4  __attribute__((ext_vector_type(4)));
typedef int    i32x4  __attribute__((ext_vector_type(4)));

// ---- pre-pass 1: svd_up [8192 x 128] f32 -> bf16, same layout ----
__global__ void k_convert_up(const float* __restrict__ up, __bf16* __restrict__ A_bf) {
    size_t t = (size_t)blockIdx.x * blockDim.x + threadIdx.x;   // 262144 threads, 4 elems each
    const float4* in4 = (const float4*)up;
    float4 v = in4[t];
    bf16x4 o = { (__bf16)v.x, (__bf16)v.y, (__bf16)v.z, (__bf16)v.w };
    *(bf16x4*)(A_bf + 4 * t) = o;
}

// ---- pre-pass 2: svd_down [128 x 8192] f32 -> Bt [8192 x 128] bf16 (transposed) ----
__global__ void k_transpose_down(const float* __restrict__ down, __bf16* __restrict__ Bt) {
    __shared__ __bf16 tile[64][132];        // +4 pad keeps 8B alignment, breaks bank stride
    int tid = threadIdx.x;
    int ib  = blockIdx.x * 64;              // i-range of this block
    int il  = tid & 63;
    int k4  = tid >> 6;
    for (int kk = 0; kk < 32; ++kk) {
        int k = kk * 4 + k4;
        tile[il][k] = (__bf16)down[(size_t)k * I_DIM + ib + il];   // coalesced 256B reads
    }
    __syncthreads();
    // output region is contiguous: Bt[ib*128 .. (ib+64)*128)
    uint2* dst = (uint2*)(Bt + (size_t)ib * RANK);
    #pragma unroll
    for (int jj = 0; jj < 8; ++jj) {
        int f   = (jj * 256 + tid) * 4;     // element index, multiple of 4
        int i_l = f >> 7;
        int k_l = f & 127;
        dst[jj * 256 + tid] = *(const uint2*)&tile[i_l][k_l];      // coalesced 8B writes
    }
}

// ---- main fused kernel: one block = 128x128 tile, 4 independent waves, ZERO LDS --
// Swapped-operand MFMA (acc = mfma(Bt_frag, A_frag, acc)) puts the OUTPUT ROW in
// lane&15 and 4 consecutive OUTPUT COLUMNS in the reg dim (same trick as attn's
// swapped QK^T). Each lane then owns out[row l15][col quad*4 + 4e'] blocks, so:
//   * weight loads are global dwordx4 straight to VGPRs (no LDS round trip)
//   * stores are dwordx4 (16 instrs/wave instead of 64)
//   * scale/zp are per-lane-row: 4+4 regs instead of 16+16
// vmcnt is FIFO, so groups are issued consumed-first and fenced with
// sched_barrier(0): frags(k0,1) | s/z | weights | MFMA(k0,1) <- gate vmcnt(24)
// leaves the 16 weight loads in flight under the MFMAs | frags(k2,3) reusing
// the same regs | MFMA(k2,3) (vmcnt(0) drains weights) | waitless epilogue.
// Frag halving keeps peak VGPR ~215 (<256): rule-20 discipline, all indices
// compile-time (r2's runtime acc index spilled 256 B/thread and doubled WRITE).
__global__ __launch_bounds__(256, 2)
void k_main(const int* __restrict__ weight, const float* __restrict__ scale,
            const float* __restrict__ zp, const __bf16* __restrict__ A_bf,
            const __bf16* __restrict__ Bt_bf, float* __restrict__ out) {
    int tid = threadIdx.x;
    int g       = blockIdx.x;               // column group == scale group (tile width 128 == GS)
    int rowbase = blockIdx.y * 128;
    int colbase = g * 128;

    int w    = tid >> 6;
    int lane = tid & 63;
    int l15  = lane & 15;
    int quad = lane >> 4;
    int wrow = (w >> 1) * 64;               // wave's 64x64 quadrant of the 128x128 tile
    int wcol = (w & 1) * 64;

    // operand frags: A[m=lane&15][k=quad*8+e], Bt[n=lane&15][k=quad*8+e]
    const __bf16* Ap = A_bf  + (size_t)(rowbase + wrow + l15) * RANK + quad * 8;
    const __bf16* Bp = Bt_bf + (size_t)(colbase + wcol + l15) * RANK + quad * 8;

    // ---- (1) frags for kc=0,1 (oldest in the vmcnt FIFO) ----
    bf16x8 af[2][4], bfr[2][4];             // [j][rb/cb], kc = j
    #pragma unroll
    for (int j = 0; j < 2; ++j)
        #pragma unroll
        for (int rb = 0; rb < 4; ++rb) {
            af[j][rb]  = *(const bf16x8*)(Ap + rb * 16 * RANK + j * 32);
            bfr[j][rb] = *(const bf16x8*)(Bp + rb * 16 * RANK + j * 32);
        }
    __builtin_amdgcn_sched_barrier(0);

    // ---- (2) scale/zp: one row per lane (row = wrow + rb*16 + l15); L2-hot ----
    float sv[4], zv[4];
    #pragma unroll
    for (int rb = 0; rb < 4; ++rb) {
        int row = rowbase + wrow + rb * 16 + l15;
        sv[rb] = scale[(size_t)row * G_DIM + g];
        zv[rb] = zp[(size_t)row * G_DIM + g];
    }
    __builtin_amdgcn_sched_barrier(0);

    // ---- (3) weight tile -> VGPRs: 16 x dwordx4, 16 KB in flight per wave ----
    i32x4 wt[4][4];
    const int* Wp = weight + (size_t)(rowbase + wrow + l15) * I_DIM
                  + colbase + wcol + quad * 4;
    #pragma unroll
    for (int rb = 0; rb < 4; ++rb)
        #pragma unroll
        for (int cb = 0; cb < 4; ++cb)
            wt[rb][cb] = *(const i32x4*)(Wp + (size_t)(rb * 16) * I_DIM + cb * 16);
    __builtin_amdgcn_sched_barrier(0);

    // ---- (4) MFMA kc=0,1: compiler gate waits frags only, weights stay in flight
    f32x4 acc[4][4];
    #pragma unroll
    for (int rb = 0; rb < 4; ++rb)
        #pragma unroll
        for (int cb = 0; cb < 4; ++cb)
            acc[rb][cb] = (f32x4){0.f, 0.f, 0.f, 0.f};

    #pragma unroll
    for (int j = 0; j < 2; ++j)
        #pragma unroll
        for (int rb = 0; rb < 4; ++rb)
            #pragma unroll
            for (int cb = 0; cb < 4; ++cb)
                acc[rb][cb] = __builtin_amdgcn_mfma_f32_16x16x32_bf16(
                    bfr[j][cb], af[j][rb], acc[rb][cb], 0, 0, 0);
    __builtin_amdgcn_sched_barrier(0);

    // ---- (5) frags for kc=2,3 reusing the SAME registers (keeps peak VGPR low)
    #pragma unroll
    for (int j = 0; j < 2; ++j)
        #pragma unroll
        for (int rb = 0; rb < 4; ++rb) {
            af[j][rb]  = *(const bf16x8*)(Ap + rb * 16 * RANK + (2 + j) * 32);
            bfr[j][rb] = *(const bf16x8*)(Bp + rb * 16 * RANK + (2 + j) * 32);
        }
    __builtin_amdgcn_sched_barrier(0);

    // ---- (6) MFMA kc=2,3 (its vmcnt(0) also drains the weight loads) ----
    #pragma unroll
    for (int j = 0; j < 2; ++j)
        #pragma unroll
        for (int rb = 0; rb < 4; ++rb)
            #pragma unroll
            for (int cb = 0; cb < 4; ++cb)
                acc[rb][cb] = __builtin_amdgcn_mfma_f32_16x16x32_bf16(
                    bfr[j][cb], af[j][rb], acc[rb][cb], 0, 0, 0);
    __builtin_amdgcn_sched_barrier(0);

    // ---- (7) epilogue: dequant + correction, 16 x dwordx4 stores, no waits ----
    // out[row = rowbase+wrow+rb*16+l15][col = colbase+wcol+cb*16+quad*4 + e]
    size_t obase = (size_t)(rowbase + wrow + l15) * I_DIM + colbase + wcol + quad * 4;
    #pragma unroll
    for (int rb = 0; rb < 4; ++rb) {
        float s = sv[rb];
        float z = zv[rb];
        #pragma unroll
        for (int cb = 0; cb < 4; ++cb) {
            f32x4 v;
            #pragma unroll
            for (int e = 0; e < 4; ++e)
                v[e] = fmaf((float)wt[rb][cb][e], s, z) + acc[rb][cb][e];
            *(f32x4*)(out + obase + (size_t)(rb * 16) * I_DIM + cb * 16) = v;
        }
    }
}

extern "C" void kernel_launch(void* const* d_in, const int* in_sizes, int n_in,
                              void* d_out, int out_size, void* d_ws, size_t ws_size,
                              hipStream_t stream) {
    const int*   weight = (const int*)d_in[0];
    const float* scale  = (const float*)d_in[1];
    const float* zp     = (const float*)d_in[2];
    const float* up     = (const float*)d_in[3];
    const float* down   = (const float*)d_in[4];
    float* out = (float*)d_out;

    __bf16* A_bf  = (__bf16*)d_ws;                  // 8192*128 bf16 = 2 MB
    __bf16* Bt_bf = A_bf + (size_t)O_DIM * RANK;    // 8192*128 bf16 = 2 MB

    k_convert_up<<<1024, 256, 0, stream>>>(up, A_bf);
    k_transpose_down<<<128, 256, 0, stream>>>(down, Bt_bf);

    dim3 grid(64, 64);   // x = column group (g), y = row tile
    k_main<<<grid, 256, 0, stream>>>(weight, scale, zp, A_bf, Bt_bf, out);
}